// Round 14
// baseline (464.709 us; speedup 1.0000x reference)
//
#include <hip/hip_runtime.h>

typedef float f4 __attribute__((ext_vector_type(4)));

// Problem constants
constexpr int Bn = 16;
constexpr int Sn = 8192;
constexpr int Dn = 256;             // D_MODEL = K_CH = OUT = 256
constexpr float kScale = 0.0625f;   // 1/sqrt(256)
constexpr int NCHUNK = 64;          // chunks (producer blocks) per batch
constexpr int NBLK   = Bn * NCHUNK; // 1024 = 256 CU x 4 blocks -> co-resident

// Workspace layout (float offsets)
constexpr int R_OFF    = 0;                     // r[B][D] = Wk @ q
constexpr int C_OFF    = R_OFF + Bn * Dn;       // c[B]
constexpr int M_OFF    = C_OFF + 64;            // chunk max   [B][NCHUNK]
constexpr int SUM_OFF  = M_OFF + Bn * NCHUNK;   // chunk expsum[B][NCHUNK]
constexpr int PART_OFF = SUM_OFF + Bn * NCHUNK; // partials    [B][NCHUNK][D]
constexpr int DONE_OFF = PART_OFF + Bn * NCHUNK * Dn;  // int done[B]

// ---------------------------------------------------------------------------
// Wave-wide float sum on the VALU pipe (DPP) — zero DS ops.
template <int CTRL>
__device__ __forceinline__ float dpp_term(float x) {
  return __builtin_bit_cast(float,
      __builtin_amdgcn_update_dpp(0, __builtin_bit_cast(int, x),
                                  CTRL, 0xf, 0xf, true));
}
__device__ __forceinline__ float wave_sum_dpp(float x) {
  x += dpp_term<0x111>(x);   // row_shr:1
  x += dpp_term<0x112>(x);   // row_shr:2
  x += dpp_term<0x114>(x);   // row_shr:4
  x += dpp_term<0x118>(x);   // row_shr:8
  x += dpp_term<0x142>(x);   // row_bcast:15
  x += dpp_term<0x143>(x);   // row_bcast:31
  return __builtin_bit_cast(float,
      __builtin_amdgcn_readlane(__builtin_bit_cast(int, x), 63));
}

// ---------------------------------------------------------------------------
// K1: per-batch tiny GEMVs: q = query@Wq + bq ; r = Wk@q ; c = q.bk
// (unchanged)
__global__ __launch_bounds__(256) void k_qrc(
    const float* __restrict__ query, const float* __restrict__ Wq,
    const float* __restrict__ bq, const float* __restrict__ Wk,
    const float* __restrict__ bk, float* __restrict__ ws) {
  int b = blockIdx.x, t = threadIdx.x;
  __shared__ float qs[Dn];
  __shared__ float qh[Dn];
  __shared__ float red[256];
  qs[t] = query[b * Dn + t];
  __syncthreads();
  float acc = bq[t];
  #pragma unroll 32
  for (int d = 0; d < Dn; ++d) acc += qs[d] * Wq[d * Dn + t];  // coalesced over t
  qh[t] = acc;
  __syncthreads();
  float racc = 0.f;
  const f4* wkrow = (const f4*)(Wk + (size_t)t * Dn);
  const f4* qh4 = (const f4*)qh;
  #pragma unroll 16
  for (int o4 = 0; o4 < Dn / 4; ++o4) {
    f4 wv = wkrow[o4];
    f4 qv = qh4[o4];
    racc += wv.x * qv.x + wv.y * qv.y + wv.z * qv.z + wv.w * qv.w;
  }
  ws[R_OFF + b * Dn + t] = racc;
  red[t] = qh[t] * bk[t];
  __syncthreads();
  for (int off = 128; off; off >>= 1) {
    if (t < off) red[t] += red[t + off];
    __syncthreads();
  }
  if (t == 0) ws[C_OFF + b] = red[0];
}

// ---------------------------------------------------------------------------
// K2 (mega v2): produce partial for chunk (b,c); signal done[b] (release);
// t0 polls with RELAXED loads + s_sleep (no invalidate storm); one acquire
// after exit; then combine + CONTIGUOUS nt-write of rows [c*128,(c+1)*128).
// grid = 1024 blocks; __launch_bounds__(256,4) + ~7KB LDS guarantee 4
// blocks/CU co-residency -> flag wait cannot deadlock.
__global__ __launch_bounds__(256, 4) void k_mega(
    const float* __restrict__ key, const float* __restrict__ value,
    const float* __restrict__ Wv, const float* __restrict__ bv,
    float* __restrict__ ws, float* __restrict__ out) {
  int blk = blockIdx.x;
  int b = blk >> 6;         // / NCHUNK
  int c = blk & 63;
  int t = threadIdx.x, lane = t & 63, wv = t >> 6;
  int cw = c * 4 + wv;      // 0..255: wave's position in the 256-row read front
  int* done = (int*)(ws + DONE_OFF);

  __shared__ float wm[4], wsum[4];
  __shared__ f4 wva[4][64];   // per-wave vacc (4 KB)
  __shared__ float msh[NCHUNK], ssh[NCHUNK], e[NCHUNK];
  __shared__ float ush[Dn], ctx[Dn];

  // ---------------- producer: online softmax over 128 rows -----------------
  f4 rv = ((const f4*)(ws + R_OFF + b * Dn))[lane] * kScale;
  float cb = ws[C_OFF + b] * kScale;
  const f4* kp = (const f4*)(key + (size_t)b * Sn * Dn);
  const f4* vp = (const f4*)(value + (size_t)b * Sn * Dn);

  float m = -1e30f, sum = 0.f;
  f4 vacc = {0.f, 0.f, 0.f, 0.f};

  f4 kv = kp[(size_t)cw * 64 + lane];
  f4 vv = vp[(size_t)cw * 64 + lane];
  #pragma unroll
  for (int i = 0; i < 32; ++i) {          // 32 rows per wave, 256 apart
    f4 kn, vn;
    if (i < 31) {                         // depth-1 prefetch
      size_t sn = (size_t)(i + 1) * 256 + cw;
      kn = kp[sn * 64 + lane];
      vn = vp[sn * 64 + lane];
    }
    float pd = kv.x * rv.x + kv.y * rv.y + kv.z * rv.z + kv.w * rv.w;
    float s = wave_sum_dpp(pd) + cb;      // uniform in all lanes
    if (s > m) {                          // wave-uniform, rare
      float sc = __expf(m - s);
      sum *= sc;
      vacc *= sc;
      m = s;
    }
    float w = __expf(s - m);
    sum += w;
    vacc += w * vv;
    kv = kn; vv = vn;
  }

  if (lane == 0) { wm[wv] = m; wsum[wv] = sum; }
  wva[wv][lane] = vacc;
  __syncthreads();

  float gm = fmaxf(fmaxf(wm[0], wm[1]), fmaxf(wm[2], wm[3]));
  float e0 = __expf(wm[0] - gm), e1 = __expf(wm[1] - gm);
  float e2 = __expf(wm[2] - gm), e3 = __expf(wm[3] - gm);
  const float* v0 = (const float*)&wva[0][0];
  const float* v1 = (const float*)&wva[1][0];
  const float* v2 = (const float*)&wva[2][0];
  const float* v3 = (const float*)&wva[3][0];
  float part = v0[t] * e0 + v1[t] * e1 + v2[t] * e2 + v3[t] * e3;
  ws[PART_OFF + ((size_t)b * NCHUNK + c) * Dn + t] = part;
  if (t == 0) {
    ws[M_OFF + b * NCHUNK + c] = gm;
    ws[SUM_OFF + b * NCHUNK + c] =
        wsum[0] * e0 + wsum[1] * e1 + wsum[2] * e2 + wsum[3] * e3;
  }

  // ---------------- signal & wait (relaxed polls, single acquire) -----------
  __threadfence();            // release: partials visible device-wide
  __syncthreads();            // all threads' stores fenced
  if (t == 0) {
    __hip_atomic_fetch_add(done + b, 1, __ATOMIC_RELEASE,
                           __HIP_MEMORY_SCOPE_AGENT);
    while (__hip_atomic_load(done + b, __ATOMIC_RELAXED,
                             __HIP_MEMORY_SCOPE_AGENT) < NCHUNK)
      __builtin_amdgcn_s_sleep(64);       // cheap idle; no cache ops
    (void)__hip_atomic_load(done + b, __ATOMIC_ACQUIRE,
                            __HIP_MEMORY_SCOPE_AGENT);  // one invalidate
  }
  __syncthreads();
  __threadfence();            // order every thread's following reads

  // ---------------- writer: LSE combine -> ctx -> contiguous nt-write ------
  if (t < NCHUNK)           msh[t] = ws[M_OFF + b * NCHUNK + t];
  else if (t < 2 * NCHUNK)  ssh[t - NCHUNK] = ws[SUM_OFF + b * NCHUNK + (t - NCHUNK)];
  __syncthreads();
  float gmb = -1e30f;
  #pragma unroll 16
  for (int k = 0; k < NCHUNK; ++k) gmb = fmaxf(gmb, msh[k]);
  if (t < NCHUNK) e[t] = __expf(msh[t] - gmb);
  __syncthreads();
  float denom = 0.f;
  #pragma unroll 16
  for (int k = 0; k < NCHUNK; ++k) denom += ssh[k] * e[k];
  float u = 0.f;
  #pragma unroll 16
  for (int k = 0; k < NCHUNK; ++k)
    u += ws[PART_OFF + ((size_t)b * NCHUNK + k) * Dn + t] * e[k];  // coalesced
  ush[t] = u / denom;
  __syncthreads();
  float acc = bv[t];
  #pragma unroll 16
  for (int o = 0; o < Dn; ++o) acc += ush[o] * Wv[o * Dn + t];  // coalesced
  ctx[t] = acc;
  __syncthreads();

  // Contiguous 128-row slice: rows [c*128, (c+1)*128), wave wv does rows
  // 4i+wv -> block covers a contiguous 128 KB region (write-combining safe).
  f4 val = ((const f4*)ctx)[lane];
  f4* op = (f4*)(out + ((size_t)b * Sn + (size_t)c * 128) * Dn);
  #pragma unroll 8
  for (int i = 0; i < 32; ++i) {
    size_t r = (size_t)i * 4 + wv;
    __builtin_nontemporal_store(val, &op[r * 64 + lane]);
  }
}

// ---------------------------------------------------------------------------
extern "C" void kernel_launch(void* const* d_in, const int* in_sizes, int n_in,
                              void* d_out, int out_size, void* d_ws, size_t ws_size,
                              hipStream_t stream) {
  const float* query = (const float*)d_in[0];
  const float* key   = (const float*)d_in[1];
  const float* value = (const float*)d_in[2];
  const float* Wq    = (const float*)d_in[3];
  const float* bq    = (const float*)d_in[4];
  const float* Wk    = (const float*)d_in[5];
  const float* bk    = (const float*)d_in[6];
  const float* Wv    = (const float*)d_in[7];
  const float* bv    = (const float*)d_in[8];
  float* out = (float*)d_out;
  float* ws  = (float*)d_ws;

  // Zero the done-flags every launch (graph-replayed too).
  hipMemsetAsync(ws + DONE_OFF, 0, Bn * sizeof(int), stream);
  hipLaunchKernelGGL(k_qrc,  dim3(Bn),   dim3(256), 0, stream,
                     query, Wq, bq, Wk, bk, ws);
  hipLaunchKernelGGL(k_mega, dim3(NBLK), dim3(256), 0, stream,
                     key, value, Wv, bv, ws, out);
}

// Round 15
// 98.516 us; speedup vs baseline: 4.7171x; 4.7171x over previous
//
#include <hip/hip_runtime.h>

typedef float f4 __attribute__((ext_vector_type(4)));  // native vector for nt ld/st

// Problem constants
constexpr int Bn = 16;
constexpr int Sn = 8192;
constexpr int Dn = 256;             // D_MODEL = K_CH = OUT = 256
constexpr float kScale = 0.0625f;   // 1/sqrt(256)
constexpr int NCHUNK = 128;         // partial-chunks per batch (128 blocks/batch)
constexpr int OBLK   = 64;          // output blocks per batch

// Workspace layout (float offsets); ~530k floats = 2.1 MB
constexpr int R_OFF    = 0;                     // r[B][D] = Wk @ q
constexpr int C_OFF    = R_OFF + Bn * Dn;       // c[B]    = q . bk
constexpr int M_OFF    = C_OFF + 64;            // chunk max   [B][NCHUNK]
constexpr int SUM_OFF  = M_OFF + Bn * NCHUNK;   // chunk expsum[B][NCHUNK]
constexpr int PART_OFF = SUM_OFF + Bn * NCHUNK; // partials    [B][NCHUNK][D]

// ---------------------------------------------------------------------------
// Full-wave (64-lane) float sum with ZERO DS-pipe ops: 6 v_add_f32_dpp on the
// VALU pipe + one readlane broadcast.
template <int CTRL>
__device__ __forceinline__ float dpp_term(float x) {
  return __builtin_bit_cast(float,
      __builtin_amdgcn_update_dpp(0, __builtin_bit_cast(int, x),
                                  CTRL, 0xf, 0xf, true));
}
__device__ __forceinline__ float wave_sum_dpp(float x) {
  x += dpp_term<0x111>(x);   // row_shr:1
  x += dpp_term<0x112>(x);   // row_shr:2
  x += dpp_term<0x114>(x);   // row_shr:4
  x += dpp_term<0x118>(x);   // row_shr:8
  x += dpp_term<0x142>(x);   // row_bcast:15
  x += dpp_term<0x143>(x);   // row_bcast:31
  return __builtin_bit_cast(float,
      __builtin_amdgcn_readlane(__builtin_bit_cast(int, x), 63));
}

// ---------------------------------------------------------------------------
// K1: per-batch tiny GEMVs: q = query@Wq + bq ; r = Wk@q ; c = q.bk
__global__ __launch_bounds__(256) void k_qrc(
    const float* __restrict__ query, const float* __restrict__ Wq,
    const float* __restrict__ bq, const float* __restrict__ Wk,
    const float* __restrict__ bk, float* __restrict__ ws) {
  int b = blockIdx.x, t = threadIdx.x;
  __shared__ float qs[Dn];
  __shared__ float qh[Dn];
  __shared__ float red[256];
  qs[t] = query[b * Dn + t];
  __syncthreads();
  float acc = bq[t];
  #pragma unroll 32
  for (int d = 0; d < Dn; ++d) acc += qs[d] * Wq[d * Dn + t];  // coalesced over t
  qh[t] = acc;
  __syncthreads();
  float racc = 0.f;
  const f4* wkrow = (const f4*)(Wk + (size_t)t * Dn);
  const f4* qh4 = (const f4*)qh;
  #pragma unroll 16
  for (int o4 = 0; o4 < Dn / 4; ++o4) {
    f4 wv = wkrow[o4];
    f4 qv = qh4[o4];
    racc += wv.x * qv.x + wv.y * qv.y + wv.z * qv.z + wv.w * qv.w;
  }
  ws[R_OFF + b * Dn + t] = racc;
  red[t] = qh[t] * bk[t];
  __syncthreads();
  for (int off = 128; off; off >>= 1) {
    if (t < off) red[t] += red[t + off];
    __syncthreads();
  }
  if (t == 0) ws[C_OFF + b] = red[0];
}

// ---------------------------------------------------------------------------
// K2 (online softmax, DPP reduce — zero DS ops in hot loop):
// block (b, c) wave wv handles rows s = i*512 + (c*4 + wv), i = 0..15.
// grid = B * NCHUNK = 2048 blocks, 256 threads
__global__ __launch_bounds__(256) void k_fused(
    const float* __restrict__ key, const float* __restrict__ value,
    float* __restrict__ ws) {
  int blk = blockIdx.x;
  int b = blk >> 7;         // / NCHUNK
  int c = blk & 127;
  int t = threadIdx.x, lane = t & 63, wv = t >> 6;
  int cw = c * 4 + wv;      // 0..511: position in the 512-row front

  __shared__ float wm[4], wsum[4];
  __shared__ f4 wva[4][64];   // per-wave vacc (4 KB)

  f4 rv = ((const f4*)(ws + R_OFF + b * Dn))[lane] * kScale;  // fold scale
  float cb = ws[C_OFF + b] * kScale;
  const f4* kp = (const f4*)(key + (size_t)b * Sn * Dn);
  const f4* vp = (const f4*)(value + (size_t)b * Sn * Dn);

  float m = -1e30f, sum = 0.f;
  f4 vacc = {0.f, 0.f, 0.f, 0.f};

  // Prologue: row-pair for i = 0
  f4 kv = kp[(size_t)cw * 64 + lane];
  f4 vv = vp[(size_t)cw * 64 + lane];

  #pragma unroll
  for (int i = 0; i < 16; ++i) {          // 16 rows per wave, 512 apart
    f4 kn, vn;
    if (i < 15) {                         // depth-1 prefetch
      size_t sn = (size_t)(i + 1) * 512 + cw;
      kn = kp[sn * 64 + lane];
      vn = vp[sn * 64 + lane];
    }
    float pd = kv.x * rv.x + kv.y * rv.y + kv.z * rv.z + kv.w * rv.w;
    float s = wave_sum_dpp(pd) + cb;      // uniform in all lanes
    if (s > m) {                          // wave-uniform branch, rare
      float sc = __expf(m - s);
      sum *= sc;
      vacc *= sc;
      m = s;
    }
    float w = __expf(s - m);
    sum += w;
    vacc += w * vv;
    kv = kn; vv = vn;
  }

  if (lane == 0) { wm[wv] = m; wsum[wv] = sum; }
  wva[wv][lane] = vacc;
  __syncthreads();

  float gm = fmaxf(fmaxf(wm[0], wm[1]), fmaxf(wm[2], wm[3]));
  float e0 = __expf(wm[0] - gm), e1 = __expf(wm[1] - gm);
  float e2 = __expf(wm[2] - gm), e3 = __expf(wm[3] - gm);
  const float* v0 = (const float*)&wva[0][0];
  const float* v1 = (const float*)&wva[1][0];
  const float* v2 = (const float*)&wva[2][0];
  const float* v3 = (const float*)&wva[3][0];
  float part = v0[t] * e0 + v1[t] * e1 + v2[t] * e2 + v3[t] * e3;
  ws[PART_OFF + ((size_t)b * NCHUNK + c) * Dn + t] = part;
  if (t == 0) {
    ws[M_OFF + b * NCHUNK + c] = gm;
    ws[SUM_OFF + b * NCHUNK + c] =
        wsum[0] * e0 + wsum[1] * e1 + wsum[2] * e2 + wsum[3] * e3;
  }
}

// ---------------------------------------------------------------------------
// K3: redundant LSE combine (L2-resident) -> ctx = (u/denom)@Wv + bv, then
// nt-write 128 rows, interleaved mapping.
// grid = B * OBLK = 1024 blocks, 256 threads
__global__ __launch_bounds__(256) void k_out(
    const float* __restrict__ Wv, const float* __restrict__ bv,
    const float* __restrict__ ws, float* __restrict__ out) {
  int blk = blockIdx.x;
  int b = blk >> 6;
  int oc = blk & 63;
  int t = threadIdx.x, lane = t & 63, wv = t >> 6;
  int cw = oc * 4 + wv;     // 0..255: position in the 256-row write front

  __shared__ float msh[NCHUNK];
  __shared__ float ssh[NCHUNK];
  __shared__ float e[NCHUNK];
  __shared__ float ush[Dn];
  __shared__ float ctx[Dn];

  if (t < NCHUNK) msh[t] = ws[M_OFF + b * NCHUNK + t];
  else            ssh[t - NCHUNK] = ws[SUM_OFF + b * NCHUNK + (t - NCHUNK)];
  __syncthreads();
  float gm = -1e30f;
  #pragma unroll 16
  for (int c = 0; c < NCHUNK; ++c) gm = fmaxf(gm, msh[c]);
  if (t < NCHUNK) e[t] = __expf(msh[t] - gm);
  __syncthreads();
  float denom = 0.f;
  #pragma unroll 16
  for (int c = 0; c < NCHUNK; ++c) denom += ssh[c] * e[c];
  float u = 0.f;
  #pragma unroll 16
  for (int c = 0; c < NCHUNK; ++c)
    u += ws[PART_OFF + ((size_t)b * NCHUNK + c) * Dn + t] * e[c];  // coalesced
  ush[t] = u / denom;
  __syncthreads();
  float acc = bv[t];
  #pragma unroll 16
  for (int o = 0; o < Dn; ++o) acc += ush[o] * Wv[o * Dn + t];  // coalesced
  ctx[t] = acc;
  __syncthreads();

  f4 val = ((const f4*)ctx)[lane];
  f4* op = (f4*)(out + (size_t)b * Sn * Dn);
  #pragma unroll 8
  for (int i = 0; i < 32; ++i) {
    size_t s = (size_t)i * 256 + cw;
    __builtin_nontemporal_store(val, &op[s * 64 + lane]);
  }
}

// ---------------------------------------------------------------------------
extern "C" void kernel_launch(void* const* d_in, const int* in_sizes, int n_in,
                              void* d_out, int out_size, void* d_ws, size_t ws_size,
                              hipStream_t stream) {
  const float* query = (const float*)d_in[0];
  const float* key   = (const float*)d_in[1];
  const float* value = (const float*)d_in[2];
  const float* Wq    = (const float*)d_in[3];
  const float* bq    = (const float*)d_in[4];
  const float* Wk    = (const float*)d_in[5];
  const float* bk    = (const float*)d_in[6];
  const float* Wv    = (const float*)d_in[7];
  const float* bv    = (const float*)d_in[8];
  float* out = (float*)d_out;
  float* ws  = (float*)d_ws;

  hipLaunchKernelGGL(k_qrc,   dim3(Bn),          dim3(256), 0, stream,
                     query, Wq, bq, Wk, bk, ws);
  hipLaunchKernelGGL(k_fused, dim3(Bn * NCHUNK), dim3(256), 0, stream,
                     key, value, ws);
  hipLaunchKernelGGL(k_out,   dim3(Bn * OBLK),   dim3(256), 0, stream,
                     Wv, bv, ws, out);
}